// Round 4
// baseline (323.214 us; speedup 1.0000x reference)
//
#include <hip/hip_runtime.h>
#include <hip/hip_bf16.h>

typedef __attribute__((ext_vector_type(8))) _Float16 half8;
typedef __attribute__((ext_vector_type(2))) __fp16 fp16x2;
typedef __attribute__((ext_vector_type(4))) float f32x4;

union UH8 {
  half8 v;
  unsigned long long q[2];
  unsigned int w[4];
};

__device__ __forceinline__ unsigned int pkh(float lo, float hi) {
  union { fp16x2 h; unsigned int u; } c;
  c.h = __builtin_amdgcn_cvt_pkrtz(lo, hi);
  return c.u;
}

constexpr int S_LEN = 2048;
constexpr int D_DIM = 64;
constexpr int KVB   = 64;     // kv tile rows
constexpr int QB    = 128;    // q rows per block (4 waves x 2 subtiles x 16)
constexpr int SKH   = 68;     // LDS row stride in f16 elems (136 B)
constexpr float LOG2E = 1.4426950408889634f;
constexpr float INV_D_QTR = 0.35355339059327373f;  // 1 / 64^0.25

__global__ __launch_bounds__(256) void attn_fwd(
    const float* __restrict__ Q, const float* __restrict__ K,
    const float* __restrict__ V, float* __restrict__ O)
{
  const int tid  = threadIdx.x;
  const int w    = tid >> 6;      // wave 0..3
  const int lane = tid & 63;
  const int m    = lane & 15;     // q-row / MFMA row index
  const int g    = lane >> 4;     // 4-lane-group index 0..3

  // XCD-aware bijective swizzle: 1024 blocks = 8 XCDs x 128; each XCD owns
  // 8 consecutive bh (16 q-blocks each) -> K/V stays hot in its private L2.
  const int bid = blockIdx.x;
  const int wg  = (bid & 7) * 128 + (bid >> 3);
  const int qb  = wg & 15;        // q-block within head
  const int bh  = wg >> 4;        // batch*head

  const int q0 = qb * QB;

  __shared__ unsigned short Ks[64 * SKH];  // K tile, [kv][d] f16
  __shared__ unsigned short Vt[64 * SKH];  // V tile transposed, [d][kv] f16

  const size_t base = (size_t)bh * S_LEN * D_DIM;

  // ---- Q fragments, fp16 (B-operand of swapped QK^T), 2 q-subtiles ----
  UH8 qf[2][2];
  #pragma unroll
  for (int sq = 0; sq < 2; ++sq) {
    const float* qp = Q + base + (size_t)(q0 + sq * 64 + w * 16 + m) * D_DIM + g * 8;
    #pragma unroll
    for (int ko = 0; ko < 2; ++ko) {
      float4 a = *(const float4*)(qp + ko * 32);
      float4 b = *(const float4*)(qp + ko * 32 + 4);
      qf[sq][ko].w[0] = pkh(a.x, a.y);
      qf[sq][ko].w[1] = pkh(a.z, a.w);
      qf[sq][ko].w[2] = pkh(b.x, b.y);
      qf[sq][ko].w[3] = pkh(b.z, b.w);
    }
  }

  f32x4 ot[2][4];   // O^T accum per subtile: ot[sq][ds] = O[q][d = ds*16+g*4+r]
  #pragma unroll
  for (int sq = 0; sq < 2; ++sq)
    #pragma unroll
    for (int ds = 0; ds < 4; ++ds) {
      f32x4 z = {0.f, 0.f, 0.f, 0.f};
      ot[sq][ds] = z;
    }
  float mrow[2] = {-1e30f, -1e30f};
  float lrow[2] = {0.f, 0.f};

  for (int t = 0; t < S_LEN / KVB; ++t) {
    const int kv0 = t * KVB;

    // ---- stage K tile -> Ks f16 (coalesced float4 reads, b64 writes) ----
    #pragma unroll
    for (int p = 0; p < 2; ++p) {
      const int idx = p * 256 + tid;       // 0..511 over 64 rows x 8 chunks
      const int row = idx >> 3, c = idx & 7;
      const float* kp = K + base + (size_t)(kv0 + row) * D_DIM + c * 8;
      float4 a = *(const float4*)kp;
      float4 b = *(const float4*)(kp + 4);
      *(unsigned long long*)&Ks[row * SKH + c * 8] =
          (unsigned long long)pkh(a.x, a.y) | ((unsigned long long)pkh(a.z, a.w) << 32);
      *(unsigned long long*)&Ks[row * SKH + c * 8 + 4] =
          (unsigned long long)pkh(b.x, b.y) | ((unsigned long long)pkh(b.z, b.w) << 32);
    }
    // ---- stage V transposed -> Vt[d][kv] f16 ----
    #pragma unroll
    for (int p = 0; p < 8; ++p) {
      const int kvp = w * 16 + p * 2;      // this wave's kv row pair
      const float* vp = V + base + (size_t)(kv0 + kvp) * D_DIM + lane;
      float a = vp[0];
      float b = vp[D_DIM];
      *(unsigned int*)&Vt[lane * SKH + kvp] = pkh(a, b);
    }
    __syncthreads();

    // ---- swapped QK^T: sv[sq][ks], lane holds S[kv = ks*16+g*4+r][q] ----
    f32x4 sv[2][4];
    #pragma unroll
    for (int ks = 0; ks < 4; ++ks) {
      f32x4 acc0 = {0.f, 0.f, 0.f, 0.f};
      f32x4 acc1 = {0.f, 0.f, 0.f, 0.f};
      #pragma unroll
      for (int ko = 0; ko < 2; ++ko) {
        UH8 ah;
        const int off = (ks * 16 + m) * SKH + ko * 32 + g * 8;
        ah.q[0] = *(const unsigned long long*)&Ks[off];
        ah.q[1] = *(const unsigned long long*)&Ks[off + 4];
        acc0 = __builtin_amdgcn_mfma_f32_16x16x32_f16(ah.v, qf[0][ko].v, acc0, 0, 0, 0);
        acc1 = __builtin_amdgcn_mfma_f32_16x16x32_f16(ah.v, qf[1][ko].v, acc1, 0, 0, 0);
      }
      sv[0][ks] = acc0;
      sv[1][ks] = acc1;
    }

    // ---- online softmax per subtile ----
    #pragma unroll
    for (int sq = 0; sq < 2; ++sq) {
      float pm = -1e30f;
      #pragma unroll
      for (int ks = 0; ks < 4; ++ks)
        pm = fmaxf(pm, fmaxf(fmaxf(sv[sq][ks][0], sv[sq][ks][1]),
                             fmaxf(sv[sq][ks][2], sv[sq][ks][3])));
      pm = fmaxf(pm, __shfl_xor(pm, 16, 64));
      pm = fmaxf(pm, __shfl_xor(pm, 32, 64));
      const float mnew = fmaxf(mrow[sq], pm);
      const float corr = exp2f((mrow[sq] - mnew) * LOG2E);
      float ps = 0.f;
      #pragma unroll
      for (int ks = 0; ks < 4; ++ks)
        #pragma unroll
        for (int r = 0; r < 4; ++r) {
          const float p = exp2f((sv[sq][ks][r] - mnew) * LOG2E);
          sv[sq][ks][r] = p;
          ps += p;
        }
      ps += __shfl_xor(ps, 16, 64);
      ps += __shfl_xor(ps, 32, 64);
      lrow[sq] = lrow[sq] * corr + ps;
      mrow[sq] = mnew;
      #pragma unroll
      for (int ds = 0; ds < 4; ++ds) {
        ot[sq][ds][0] *= corr; ot[sq][ds][1] *= corr;
        ot[sq][ds][2] *= corr; ot[sq][ds][3] *= corr;
      }
    }

    // ---- swapped PV: O^T += V^T x P^T (V-fragment shared by both subtiles) ----
    #pragma unroll
    for (int kk = 0; kk < 2; ++kk) {
      UH8 pf[2];
      #pragma unroll
      for (int sq = 0; sq < 2; ++sq) {
        const unsigned int a0 = pkh(sv[sq][2 * kk][0], sv[sq][2 * kk][1]);
        const unsigned int a1 = pkh(sv[sq][2 * kk][2], sv[sq][2 * kk][3]);
        const unsigned int b0 = pkh(sv[sq][2 * kk + 1][0], sv[sq][2 * kk + 1][1]);
        const unsigned int b1 = pkh(sv[sq][2 * kk + 1][2], sv[sq][2 * kk + 1][3]);
        const int srcA = m + ((lane & 16) << 1);   // q + 32*(g&1)
        const int srcB = srcA + 16;
        const unsigned int lo0 = (unsigned int)__shfl((int)a0, srcA, 64);
        const unsigned int lo1 = (unsigned int)__shfl((int)a1, srcA, 64);
        const unsigned int lo2 = (unsigned int)__shfl((int)a0, srcB, 64);
        const unsigned int lo3 = (unsigned int)__shfl((int)a1, srcB, 64);
        const unsigned int hi0 = (unsigned int)__shfl((int)b0, srcA, 64);
        const unsigned int hi1 = (unsigned int)__shfl((int)b1, srcA, 64);
        const unsigned int hi2 = (unsigned int)__shfl((int)b0, srcB, 64);
        const unsigned int hi3 = (unsigned int)__shfl((int)b1, srcB, 64);
        const bool up = (g >> 1) != 0;
        pf[sq].w[0] = up ? hi0 : lo0;
        pf[sq].w[1] = up ? hi1 : lo1;
        pf[sq].w[2] = up ? hi2 : lo2;
        pf[sq].w[3] = up ? hi3 : lo3;
      }
      #pragma unroll
      for (int ds = 0; ds < 4; ++ds) {
        UH8 vf;
        const int off = (ds * 16 + m) * SKH + kk * 32 + g * 8;
        vf.q[0] = *(const unsigned long long*)&Vt[off];
        vf.q[1] = *(const unsigned long long*)&Vt[off + 4];
        ot[0][ds] = __builtin_amdgcn_mfma_f32_16x16x32_f16(vf.v, pf[0].v, ot[0][ds], 0, 0, 0);
        ot[1][ds] = __builtin_amdgcn_mfma_f32_16x16x32_f16(vf.v, pf[1].v, ot[1][ds], 0, 0, 0);
      }
    }
    __syncthreads();
  }

  // ---- epilogue: out = O^T-acc * (dim^-0.25 / l), coalesced float4 stores ----
  #pragma unroll
  for (int sq = 0; sq < 2; ++sq) {
    const float inv = INV_D_QTR / lrow[sq];
    #pragma unroll
    for (int ds = 0; ds < 4; ++ds) {
      f32x4 o = ot[sq][ds] * inv;
      float* op = O + base + (size_t)(q0 + sq * 64 + w * 16 + m) * D_DIM + ds * 16 + g * 4;
      *(f32x4*)op = o;
    }
  }
}

extern "C" void kernel_launch(void* const* d_in, const int* in_sizes, int n_in,
                              void* d_out, int out_size, void* d_ws, size_t ws_size,
                              hipStream_t stream) {
  const float* q = (const float*)d_in[0];
  const float* k = (const float*)d_in[1];
  const float* v = (const float*)d_in[2];
  float* o = (float*)d_out;
  const int nblocks = (S_LEN / QB) * 64;   // 16 q-blocks x 64 bh = 1024
  attn_fwd<<<dim3(nblocks), dim3(256), 0, stream>>>(q, k, v, o);
}

// Round 5
// 164.360 us; speedup vs baseline: 1.9665x; 1.9665x over previous
//
#include <hip/hip_runtime.h>
#include <hip/hip_bf16.h>

typedef __attribute__((ext_vector_type(8))) _Float16 half8;
typedef __attribute__((ext_vector_type(2))) __fp16 fp16x2;
typedef __attribute__((ext_vector_type(4))) float f32x4;

union UH8 {
  half8 v;
  unsigned long long q[2];
  unsigned int w[4];
};

__device__ __forceinline__ unsigned int pkh(float lo, float hi) {
  union { fp16x2 h; unsigned int u; } c;
  c.h = __builtin_amdgcn_cvt_pkrtz(lo, hi);
  return c.u;
}

constexpr int S_LEN = 2048;
constexpr int D_DIM = 64;
constexpr int KVB   = 64;     // kv tile rows
constexpr int QB    = 128;    // q rows per block (4 waves x 2 subtiles x 16)
constexpr int SKH   = 68;     // LDS row stride in f16 elems (136 B)
constexpr int TILE  = 64 * SKH;
constexpr int NT    = S_LEN / KVB;
constexpr float LOG2E = 1.4426950408889634f;
constexpr float INV_D_QTR = 0.35355339059327373f;  // 1 / 64^0.25

__global__ __launch_bounds__(256) void attn_fwd(
    const float* __restrict__ Q, const float* __restrict__ K,
    const float* __restrict__ V, float* __restrict__ O)
{
  const int tid  = threadIdx.x;
  const int w    = tid >> 6;      // wave 0..3
  const int lane = tid & 63;
  const int m    = lane & 15;     // q-row / MFMA row index
  const int g    = lane >> 4;     // 4-lane-group index 0..3

  // XCD-aware bijective swizzle: 1024 blocks = 8 XCDs x 128; each XCD owns
  // 8 consecutive bh -> K/V stays hot in its private L2.
  const int bid = blockIdx.x;
  const int wg  = (bid & 7) * 128 + (bid >> 3);
  const int qb  = wg & 15;        // q-block within head
  const int bh  = wg >> 4;        // batch*head

  const int q0 = qb * QB;

  __shared__ unsigned short KsB[2][TILE];  // K tile, [kv][d] f16, double-buffered
  __shared__ unsigned short VtB[2][TILE];  // V^T tile, [d][kv] f16, double-buffered

  const size_t base = (size_t)bh * S_LEN * D_DIM;

  // ---- staging ownership ----
  const int kr = tid >> 3;             // K row 0..31 (and +32)
  const int kc = (tid & 7) * 8;        // K col elem offset

  // prefetch registers
  float4 ka0, kb0, ka1, kb1;
  float va[8], vb[8];

  auto PREF = [&](int tt) {
    const int kv0 = tt * KVB;
    const float* kp = K + base + (size_t)(kv0 + kr) * D_DIM + kc;
    ka0 = *(const float4*)kp;
    kb0 = *(const float4*)(kp + 4);
    const float* kp1 = kp + 32 * D_DIM;
    ka1 = *(const float4*)kp1;
    kb1 = *(const float4*)(kp1 + 4);
    const float* vp = V + base + (size_t)(kv0 + w * 16) * D_DIM + lane;
    #pragma unroll
    for (int p = 0; p < 8; ++p) {
      va[p] = vp[(2 * p) * D_DIM];
      vb[p] = vp[(2 * p + 1) * D_DIM];
    }
  };

  auto WRITE = [&](int b) {
    unsigned short* kd = KsB[b];
    *(unsigned long long*)&kd[kr * SKH + kc] =
        (unsigned long long)pkh(ka0.x, ka0.y) | ((unsigned long long)pkh(ka0.z, ka0.w) << 32);
    *(unsigned long long*)&kd[kr * SKH + kc + 4] =
        (unsigned long long)pkh(kb0.x, kb0.y) | ((unsigned long long)pkh(kb0.z, kb0.w) << 32);
    *(unsigned long long*)&kd[(kr + 32) * SKH + kc] =
        (unsigned long long)pkh(ka1.x, ka1.y) | ((unsigned long long)pkh(ka1.z, ka1.w) << 32);
    *(unsigned long long*)&kd[(kr + 32) * SKH + kc + 4] =
        (unsigned long long)pkh(kb1.x, kb1.y) | ((unsigned long long)pkh(kb1.z, kb1.w) << 32);
    unsigned short* vd = VtB[b];
    #pragma unroll
    for (int p = 0; p < 8; ++p)
      *(unsigned int*)&vd[lane * SKH + w * 16 + 2 * p] = pkh(va[p], vb[p]);
  };

  // ---- Q fragments, fp16 (B-operand of swapped QK^T), 2 q-subtiles ----
  UH8 qf[2][2];
  #pragma unroll
  for (int sq = 0; sq < 2; ++sq) {
    const float* qp = Q + base + (size_t)(q0 + sq * 64 + w * 16 + m) * D_DIM + g * 8;
    #pragma unroll
    for (int ko = 0; ko < 2; ++ko) {
      float4 a = *(const float4*)(qp + ko * 32);
      float4 b = *(const float4*)(qp + ko * 32 + 4);
      qf[sq][ko].w[0] = pkh(a.x, a.y);
      qf[sq][ko].w[1] = pkh(a.z, a.w);
      qf[sq][ko].w[2] = pkh(b.x, b.y);
      qf[sq][ko].w[3] = pkh(b.z, b.w);
    }
  }

  f32x4 ot[2][4];
  #pragma unroll
  for (int sq = 0; sq < 2; ++sq)
    #pragma unroll
    for (int ds = 0; ds < 4; ++ds) {
      f32x4 z = {0.f, 0.f, 0.f, 0.f};
      ot[sq][ds] = z;
    }
  float mrow[2] = {-1e30f, -1e30f};
  float lrow[2] = {0.f, 0.f};

  // prologue: stage tile 0 into buffer 0
  PREF(0);
  WRITE(0);

  for (int t = 0; t < NT; ++t) {
    const bool more = (t + 1 < NT);
    if (more) PREF(t + 1);     // issue next tile's loads; latency hides under compute
    __syncthreads();           // buf[t&1] staged by all waves
    const int cb = t & 1;
    const unsigned short* ksc = KsB[cb];
    const unsigned short* vtc = VtB[cb];

    // ---- swapped QK^T: sv[sq][ks], lane holds S[kv = ks*16+g*4+r][q] ----
    f32x4 sv[2][4];
    #pragma unroll
    for (int ks = 0; ks < 4; ++ks) {
      f32x4 acc0 = {0.f, 0.f, 0.f, 0.f};
      f32x4 acc1 = {0.f, 0.f, 0.f, 0.f};
      #pragma unroll
      for (int ko = 0; ko < 2; ++ko) {
        UH8 ah;
        const int off = (ks * 16 + m) * SKH + ko * 32 + g * 8;
        ah.q[0] = *(const unsigned long long*)&ksc[off];
        ah.q[1] = *(const unsigned long long*)&ksc[off + 4];
        acc0 = __builtin_amdgcn_mfma_f32_16x16x32_f16(ah.v, qf[0][ko].v, acc0, 0, 0, 0);
        acc1 = __builtin_amdgcn_mfma_f32_16x16x32_f16(ah.v, qf[1][ko].v, acc1, 0, 0, 0);
      }
      sv[0][ks] = acc0;
      sv[1][ks] = acc1;
    }

    // ---- online softmax per subtile ----
    #pragma unroll
    for (int sq = 0; sq < 2; ++sq) {
      float pm = -1e30f;
      #pragma unroll
      for (int ks = 0; ks < 4; ++ks)
        pm = fmaxf(pm, fmaxf(fmaxf(sv[sq][ks][0], sv[sq][ks][1]),
                             fmaxf(sv[sq][ks][2], sv[sq][ks][3])));
      pm = fmaxf(pm, __shfl_xor(pm, 16, 64));
      pm = fmaxf(pm, __shfl_xor(pm, 32, 64));
      const float mnew = fmaxf(mrow[sq], pm);
      const float corr = __builtin_amdgcn_exp2f((mrow[sq] - mnew) * LOG2E);
      float ps = 0.f;
      #pragma unroll
      for (int ks = 0; ks < 4; ++ks)
        #pragma unroll
        for (int r = 0; r < 4; ++r) {
          const float p = __builtin_amdgcn_exp2f((sv[sq][ks][r] - mnew) * LOG2E);
          sv[sq][ks][r] = p;
          ps += p;
        }
      ps += __shfl_xor(ps, 16, 64);
      ps += __shfl_xor(ps, 32, 64);
      lrow[sq] = lrow[sq] * corr + ps;
      mrow[sq] = mnew;
      #pragma unroll
      for (int ds = 0; ds < 4; ++ds) {
        ot[sq][ds][0] *= corr; ot[sq][ds][1] *= corr;
        ot[sq][ds][2] *= corr; ot[sq][ds][3] *= corr;
      }
    }

    // ---- swapped PV: O^T += V^T x P^T ----
    #pragma unroll
    for (int kk = 0; kk < 2; ++kk) {
      UH8 pf[2];
      #pragma unroll
      for (int sq = 0; sq < 2; ++sq) {
        const unsigned int a0 = pkh(sv[sq][2 * kk][0], sv[sq][2 * kk][1]);
        const unsigned int a1 = pkh(sv[sq][2 * kk][2], sv[sq][2 * kk][3]);
        const unsigned int b0 = pkh(sv[sq][2 * kk + 1][0], sv[sq][2 * kk + 1][1]);
        const unsigned int b1 = pkh(sv[sq][2 * kk + 1][2], sv[sq][2 * kk + 1][3]);
        const int srcA = m + ((lane & 16) << 1);   // q + 32*(g&1)
        const int srcB = srcA + 16;
        const unsigned int lo0 = (unsigned int)__shfl((int)a0, srcA, 64);
        const unsigned int lo1 = (unsigned int)__shfl((int)a1, srcA, 64);
        const unsigned int lo2 = (unsigned int)__shfl((int)a0, srcB, 64);
        const unsigned int lo3 = (unsigned int)__shfl((int)a1, srcB, 64);
        const unsigned int hi0 = (unsigned int)__shfl((int)b0, srcA, 64);
        const unsigned int hi1 = (unsigned int)__shfl((int)b1, srcA, 64);
        const unsigned int hi2 = (unsigned int)__shfl((int)b0, srcB, 64);
        const unsigned int hi3 = (unsigned int)__shfl((int)b1, srcB, 64);
        const bool up = (g >> 1) != 0;
        pf[sq].w[0] = up ? hi0 : lo0;
        pf[sq].w[1] = up ? hi1 : lo1;
        pf[sq].w[2] = up ? hi2 : lo2;
        pf[sq].w[3] = up ? hi3 : lo3;
      }
      #pragma unroll
      for (int ds = 0; ds < 4; ++ds) {
        UH8 vf;
        const int off = (ds * 16 + m) * SKH + kk * 32 + g * 8;
        vf.q[0] = *(const unsigned long long*)&vtc[off];
        vf.q[1] = *(const unsigned long long*)&vtc[off + 4];
        ot[0][ds] = __builtin_amdgcn_mfma_f32_16x16x32_f16(vf.v, pf[0].v, ot[0][ds], 0, 0, 0);
        ot[1][ds] = __builtin_amdgcn_mfma_f32_16x16x32_f16(vf.v, pf[1].v, ot[1][ds], 0, 0, 0);
      }
    }

    if (more) WRITE(1 - cb);   // loads have had the whole compute phase to land
  }

  // ---- epilogue ----
  #pragma unroll
  for (int sq = 0; sq < 2; ++sq) {
    const float inv = INV_D_QTR / lrow[sq];
    #pragma unroll
    for (int ds = 0; ds < 4; ++ds) {
      f32x4 o = ot[sq][ds] * inv;
      float* op = O + base + (size_t)(q0 + sq * 64 + w * 16 + m) * D_DIM + ds * 16 + g * 4;
      *(f32x4*)op = o;
    }
  }
}

extern "C" void kernel_launch(void* const* d_in, const int* in_sizes, int n_in,
                              void* d_out, int out_size, void* d_ws, size_t ws_size,
                              hipStream_t stream) {
  const float* q = (const float*)d_in[0];
  const float* k = (const float*)d_in[1];
  const float* v = (const float*)d_in[2];
  float* o = (float*)d_out;
  const int nblocks = (S_LEN / QB) * 64;   // 16 q-blocks x 64 bh = 1024
  attn_fwd<<<dim3(nblocks), dim3(256), 0, stream>>>(q, k, v, o);
}

// Round 7
// 130.148 us; speedup vs baseline: 2.4834x; 1.2629x over previous
//
#include <hip/hip_runtime.h>
#include <hip/hip_bf16.h>

typedef __attribute__((ext_vector_type(8))) _Float16 half8;
typedef __attribute__((ext_vector_type(2))) __fp16 fp16x2;
typedef __attribute__((ext_vector_type(4))) float f32x4;
typedef __attribute__((ext_vector_type(16))) float f32x16;

union UH8 {
  half8 v;
  unsigned long long q[2];
  unsigned int w[4];
};

__device__ __forceinline__ unsigned int pkh(float lo, float hi) {
  union { fp16x2 h; unsigned int u; } c;
  c.h = __builtin_amdgcn_cvt_pkrtz(lo, hi);
  return c.u;
}

constexpr int S_LEN = 2048;
constexpr int D_DIM = 64;
constexpr int KVB   = 64;     // kv tile rows
constexpr int QB    = 128;    // q rows per block (4 waves x 32)
constexpr int SKH   = 68;     // LDS row stride in f16 elems (136 B)
constexpr int TILE  = 64 * SKH;
constexpr int NT    = S_LEN / KVB;
constexpr float LOG2E = 1.4426950408889634f;
constexpr float INV_D_QTR = 0.35355339059327373f;  // 1 / 64^0.25

__global__ __launch_bounds__(256) void attn_fwd(
    const float* __restrict__ Q, const float* __restrict__ K,
    const float* __restrict__ V, float* __restrict__ O)
{
  const int tid  = threadIdx.x;
  const int w    = tid >> 6;      // wave 0..3
  const int lane = tid & 63;
  const int q32  = lane & 31;     // q-row within wave tile / MFMA m,n index
  const int h    = lane >> 5;     // half-wave index

  // XCD-aware bijective swizzle (1024 = 8 x 128)
  const int bid = blockIdx.x;
  const int wg  = (bid & 7) * 128 + (bid >> 3);
  const int qb  = wg & 15;        // q-block within head
  const int bh  = wg >> 4;        // batch*head

  const int q0 = qb * QB;

  __shared__ unsigned short KsB[2][TILE];  // K tile [kv][d] f16, double-buffered
  __shared__ unsigned short VtB[2][TILE];  // V^T tile [d][kv] f16, double-buffered

  const size_t base = (size_t)bh * S_LEN * D_DIM;

  // ---- staging ownership ----
  const int kr = tid >> 3;             // K row 0..31 (and +32)
  const int kc = (tid & 7) * 8;        // K col elem offset

  float4 ka0, kb0, ka1, kb1;
  float va[8], vb[8];

  auto PREF = [&](int tt) {
    const int kv0 = tt * KVB;
    const float* kp = K + base + (size_t)(kv0 + kr) * D_DIM + kc;
    ka0 = *(const float4*)kp;
    kb0 = *(const float4*)(kp + 4);
    const float* kp1 = kp + 32 * D_DIM;
    ka1 = *(const float4*)kp1;
    kb1 = *(const float4*)(kp1 + 4);
    const float* vp = V + base + (size_t)(kv0 + w * 16) * D_DIM + lane;
    #pragma unroll
    for (int p = 0; p < 8; ++p) {
      va[p] = vp[(2 * p) * D_DIM];
      vb[p] = vp[(2 * p + 1) * D_DIM];
    }
  };

  auto WRITE = [&](int b) {
    unsigned short* kd = KsB[b];
    *(unsigned long long*)&kd[kr * SKH + kc] =
        (unsigned long long)pkh(ka0.x, ka0.y) | ((unsigned long long)pkh(ka0.z, ka0.w) << 32);
    *(unsigned long long*)&kd[kr * SKH + kc + 4] =
        (unsigned long long)pkh(kb0.x, kb0.y) | ((unsigned long long)pkh(kb0.z, kb0.w) << 32);
    *(unsigned long long*)&kd[(kr + 32) * SKH + kc] =
        (unsigned long long)pkh(ka1.x, ka1.y) | ((unsigned long long)pkh(ka1.z, ka1.w) << 32);
    *(unsigned long long*)&kd[(kr + 32) * SKH + kc + 4] =
        (unsigned long long)pkh(kb1.x, kb1.y) | ((unsigned long long)pkh(kb1.z, kb1.w) << 32);
    unsigned short* vd = VtB[b];
    #pragma unroll
    for (int p = 0; p < 8; ++p)
      *(unsigned int*)&vd[lane * SKH + w * 16 + 2 * p] = pkh(va[p], vb[p]);
  };

  // ---- Q fragments fp16: qf[s] holds Q[q32][k = s*16 + h*8 + j], j=0..7 ----
  UH8 qf[4];
  {
    const float* qp = Q + base + (size_t)(q0 + w * 32 + q32) * D_DIM;
    #pragma unroll
    for (int s = 0; s < 4; ++s) {
      float4 a = *(const float4*)(qp + s * 16 + h * 8);
      float4 b = *(const float4*)(qp + s * 16 + h * 8 + 4);
      qf[s].w[0] = pkh(a.x, a.y);
      qf[s].w[1] = pkh(a.z, a.w);
      qf[s].w[2] = pkh(b.x, b.y);
      qf[s].w[3] = pkh(b.z, b.w);
    }
  }

  // O^T accum: oc[dt] reg r -> O[d = dt*32 + (r&3) + 8*(r>>2) + 4h][q = q32]
  f32x16 oc[2] = {
    {0,0,0,0,0,0,0,0,0,0,0,0,0,0,0,0},
    {0,0,0,0,0,0,0,0,0,0,0,0,0,0,0,0}
  };
  float mrow = -1e30f;
  float lrow = 0.f;

  PREF(0);
  WRITE(0);

  for (int t = 0; t < NT; ++t) {
    const bool more = (t + 1 < NT);
    if (more) PREF(t + 1);     // latency hides under compute
    __syncthreads();
    const int cb = t & 1;
    const unsigned short* ksc = KsB[cb];
    const unsigned short* vtc = VtB[cb];

    // ---- swapped QK^T (32x32x16): sc[kvt] reg r = S[kv = kvt*32 + (r&3)+8*(r>>2)+4h][q32]
    f32x16 sc[2];
    #pragma unroll
    for (int kvt = 0; kvt < 2; ++kvt) {
      f32x16 acc = {0,0,0,0,0,0,0,0,0,0,0,0,0,0,0,0};
      #pragma unroll
      for (int s = 0; s < 4; ++s) {
        UH8 af;
        const int off = (kvt * 32 + q32) * SKH + s * 16 + h * 8;
        af.q[0] = *(const unsigned long long*)&ksc[off];
        af.q[1] = *(const unsigned long long*)&ksc[off + 4];
        acc = __builtin_amdgcn_mfma_f32_32x32x16_f16(af.v, qf[s].v, acc, 0, 0, 0);
      }
      sc[kvt] = acc;
    }

    // ---- online softmax: row q32 lives in lanes {q32, q32+32} ----
    float pm = -1e30f;
    #pragma unroll
    for (int kvt = 0; kvt < 2; ++kvt)
      #pragma unroll
      for (int i = 0; i < 16; ++i)
        pm = fmaxf(pm, sc[kvt][i]);
    pm = fmaxf(pm, __shfl_xor(pm, 32, 64));
    const float mnew = fmaxf(mrow, pm);
    const float corr = __builtin_amdgcn_exp2f((mrow - mnew) * LOG2E);
    float ps = 0.f;
    #pragma unroll
    for (int kvt = 0; kvt < 2; ++kvt)
      #pragma unroll
      for (int i = 0; i < 16; ++i) {
        const float e = __builtin_amdgcn_exp2f((sc[kvt][i] - mnew) * LOG2E);
        sc[kvt][i] = e;
        ps += e;
      }
    ps += __shfl_xor(ps, 32, 64);
    lrow = lrow * corr + ps;
    mrow = mnew;
    #pragma unroll
    for (int dt = 0; dt < 2; ++dt)
      #pragma unroll
      for (int i = 0; i < 16; ++i)
        oc[dt][i] *= corr;

    // ---- swapped PV (32x32x16): O^T += V^T x P^T, P-frag via permlane32_swap ----
    #pragma unroll
    for (int s = 0; s < 4; ++s) {
      const int kvt = s >> 1;
      const int sr  = (s & 1) * 8;
      unsigned int LO0 = pkh(sc[kvt][sr + 0], sc[kvt][sr + 1]);
      unsigned int LO1 = pkh(sc[kvt][sr + 2], sc[kvt][sr + 3]);
      unsigned int HI0 = pkh(sc[kvt][sr + 4], sc[kvt][sr + 5]);
      unsigned int HI1 = pkh(sc[kvt][sr + 6], sc[kvt][sr + 7]);
      // v_permlane32_swap_b32 vdst, vsrc: vdst's HIGH 32 lanes <-> vsrc's LOW 32 lanes.
      // swap(LO, HI): LO(h=1) <- HI(h=0), HI(h=0) <- LO(h=1).
      // After: h=0 lane: {LO = own LO, HI = LO(h=1)}; h=1 lane: {LO = HI(h=0), HI = own HI}
      //   -> pf.w[0]=LO, pf.w[2]=HI gives B-frag words in kv order for both halves.
      asm("v_permlane32_swap_b32 %0, %1" : "+v"(LO0), "+v"(HI0));
      asm("v_permlane32_swap_b32 %0, %1" : "+v"(LO1), "+v"(HI1));
      UH8 pf;
      pf.w[0] = LO0;
      pf.w[1] = LO1;
      pf.w[2] = HI0;
      pf.w[3] = HI1;
      #pragma unroll
      for (int dt = 0; dt < 2; ++dt) {
        UH8 vf;
        const int off = (dt * 32 + q32) * SKH + s * 16 + h * 8;
        vf.q[0] = *(const unsigned long long*)&vtc[off];
        vf.q[1] = *(const unsigned long long*)&vtc[off + 4];
        oc[dt] = __builtin_amdgcn_mfma_f32_32x32x16_f16(vf.v, pf.v, oc[dt], 0, 0, 0);
      }
    }

    if (more) WRITE(1 - cb);
  }

  // ---- epilogue: O[q][d] = oc * (dim^-0.25 / l) ----
  const float inv = INV_D_QTR / lrow;
  float* orow = O + base + (size_t)(q0 + w * 32 + q32) * D_DIM;
  #pragma unroll
  for (int dt = 0; dt < 2; ++dt)
    #pragma unroll
    for (int r1 = 0; r1 < 4; ++r1) {
      f32x4 o = { oc[dt][4 * r1 + 0] * inv, oc[dt][4 * r1 + 1] * inv,
                  oc[dt][4 * r1 + 2] * inv, oc[dt][4 * r1 + 3] * inv };
      *(f32x4*)(orow + dt * 32 + 8 * r1 + 4 * h) = o;
    }
}

extern "C" void kernel_launch(void* const* d_in, const int* in_sizes, int n_in,
                              void* d_out, int out_size, void* d_ws, size_t ws_size,
                              hipStream_t stream) {
  const float* q = (const float*)d_in[0];
  const float* k = (const float*)d_in[1];
  const float* v = (const float*)d_in[2];
  float* o = (float*)d_out;
  const int nblocks = (S_LEN / QB) * 64;   // 16 q-blocks x 64 bh = 1024
  attn_fwd<<<dim3(nblocks), dim3(256), 0, stream>>>(q, k, v, o);
}